// Round 1
// baseline (554.325 us; speedup 1.0000x reference)
//
#include <hip/hip_runtime.h>
#include <stdint.h>

typedef __attribute__((ext_vector_type(8))) short short8;
typedef __attribute__((ext_vector_type(4))) float floatx4;

// ---------- helpers ----------
__device__ __forceinline__ unsigned short f2b(float f) {
    union { float f; uint32_t u; } v; v.f = f;
    uint32_t u = v.u;
    return (unsigned short)((u + 0x7FFFu + ((u >> 16) & 1u)) >> 16);  // RNE
}

__device__ __forceinline__ void async16(const void* g, void* l) {
    __builtin_amdgcn_global_load_lds(
        (const __attribute__((address_space(1))) void*)g,
        (__attribute__((address_space(3))) void*)l, 16, 0, 0);
}

// ---------- kernel 1: L2-normalize rows, emit bf16 ----------
__global__ void norm_kernel(const float* __restrict__ in,
                            unsigned short* __restrict__ xb, int D) {
    int b = blockIdx.x, t = threadIdx.x;
    const float* row = in + (size_t)b * D;
    float ss = 0.f;
    for (int i = t * 4; i < D; i += 1024) {
        float4 v = *(const float4*)(row + i);
        ss += v.x * v.x + v.y * v.y + v.z * v.z + v.w * v.w;
    }
    for (int off = 32; off > 0; off >>= 1) ss += __shfl_down(ss, off);
    __shared__ float wsum[4];
    __shared__ float rn_sh;
    if ((t & 63) == 0) wsum[t >> 6] = ss;
    __syncthreads();
    if (t == 0) rn_sh = rsqrtf(wsum[0] + wsum[1] + wsum[2] + wsum[3]);
    __syncthreads();
    float rn = rn_sh;
    unsigned short* orow = xb + (size_t)b * D;
    for (int i = t * 4; i < D; i += 1024) {
        float4 v = *(const float4*)(row + i);
        ushort4 o;
        o.x = f2b(v.x * rn); o.y = f2b(v.y * rn);
        o.z = f2b(v.z * rn); o.w = f2b(v.w * rn);
        *(ushort4*)(orow + i) = o;
    }
}

// ---------- kernel 2: fused GEMM ----------
// BM=256 (full batch), BN=64, BK=32.  blocks [0,nbF): features w/ fused
// exp-sum epilogue + finch_pos capture; blocks [nbF, nbF+nbC): centroids,
// store scores to km.
__global__ __launch_bounds__(256, 2)
void gemm_kernel(const unsigned short* __restrict__ xb,
                 const float* __restrict__ featB,
                 const float* __restrict__ centB,
                 const int* __restrict__ targets,
                 float* __restrict__ S, float* __restrict__ pos,
                 float* __restrict__ km,
                 int D, int N, int K, int nbF) {
    __shared__ __align__(16) unsigned short Alds[256 * 32];  // 16 KB, rows of 64 B
    __shared__ __align__(16) unsigned short Blds[64 * 32];   // 4 KB

    const int t = threadIdx.x;
    const int w = t >> 6, l = t & 63;
    const bool isFeat = ((int)blockIdx.x < nbF);
    const int n0 = (isFeat ? (int)blockIdx.x : ((int)blockIdx.x - nbF)) * 64;
    const float* Bsrc = isFeat ? featB : centB;

    floatx4 acc[4][4];
#pragma unroll
    for (int ti = 0; ti < 4; ++ti)
#pragma unroll
        for (int tj = 0; tj < 4; ++tj)
            acc[ti][tj] = (floatx4){0.f, 0.f, 0.f, 0.f};

    const int kIters = D / 32;
    const int br = t >> 2, bp = t & 3;                 // B staging: 4 thr/row
    const float* bptr = Bsrc + (size_t)(n0 + br) * D + bp * 8;

    for (int kt = 0; kt < kIters; ++kt) {
        // stage A (bf16, direct-to-LDS, 16 B per lane per issue)
#pragma unroll
        for (int j = 0; j < 4; ++j) {
            int bo = (j * 256 + t) * 16;               // byte offset in 16 KB tile
            int arow = bo >> 6, ic = bo & 63;
            async16((const char*)xb + (size_t)arow * (D * 2) + (size_t)kt * 64 + ic,
                    (char*)Alds + bo);
        }
        // stage B: fp32 load -> bf16 cvt -> LDS
        {
            const float* bg = bptr + kt * 32;
            float4 f0 = *(const float4*)bg;
            float4 f1 = *(const float4*)(bg + 4);
            short8 bv;
            bv[0] = (short)f2b(f0.x); bv[1] = (short)f2b(f0.y);
            bv[2] = (short)f2b(f0.z); bv[3] = (short)f2b(f0.w);
            bv[4] = (short)f2b(f1.x); bv[5] = (short)f2b(f1.y);
            bv[6] = (short)f2b(f1.z); bv[7] = (short)f2b(f1.w);
            *(short8*)((char*)Blds + br * 64 + bp * 16) = bv;
        }
        __syncthreads();

        short8 aF[4], bF[4];
#pragma unroll
        for (int ti = 0; ti < 4; ++ti)
            aF[ti] = *(const short8*)((const char*)Alds +
                      (w * 64 + ti * 16 + (l & 15)) * 64 + ((l >> 4) * 16));
#pragma unroll
        for (int tj = 0; tj < 4; ++tj)
            bF[tj] = *(const short8*)((const char*)Blds +
                      (tj * 16 + (l & 15)) * 64 + ((l >> 4) * 16));
#pragma unroll
        for (int ti = 0; ti < 4; ++ti)
#pragma unroll
            for (int tj = 0; tj < 4; ++tj)
                acc[ti][tj] = __builtin_amdgcn_mfma_f32_16x16x32_bf16(
                    aF[ti], bF[tj], acc[ti][tj], 0, 0, 0);
        __syncthreads();
    }

    // epilogue.  C/D layout: col = l&15, row = (l>>4)*4 + reg  [m89-verified]
    if (isFeat) {
#pragma unroll
        for (int ti = 0; ti < 4; ++ti) {
#pragma unroll
            for (int r = 0; r < 4; ++r) {
                int row = w * 64 + ti * 16 + ((l >> 4) << 2) + r;
                int tr = targets[row];
                int col0 = n0 + (l & 15);
                float e = 0.f;
#pragma unroll
                for (int tj = 0; tj < 4; ++tj) {
                    float c = acc[ti][tj][r];
                    e += __expf(c * 20.0f);            // |c|<=~1 -> exp<=e^20, safe
                    if (tr == col0 + tj * 16) pos[row] = c;
                }
                // sum over the 16 cols (consecutive 16-lane group)
                e += __shfl_xor(e, 1); e += __shfl_xor(e, 2);
                e += __shfl_xor(e, 4); e += __shfl_xor(e, 8);
                if ((l & 15) == 0) atomicAdd(&S[row], e);
            }
        }
    } else {
#pragma unroll
        for (int ti = 0; ti < 4; ++ti) {
#pragma unroll
            for (int r = 0; r < 4; ++r) {
                int row = w * 64 + ti * 16 + ((l >> 4) << 2) + r;
                size_t base = (size_t)row * K + n0 + (l & 15);
#pragma unroll
                for (int tj = 0; tj < 4; ++tj)
                    km[base + tj * 16] = acc[ti][tj][r];
            }
        }
    }
}

// ---------- kernel 3: per-row top-neg_size of masked kmeans scores ----------
__global__ void topk_kernel(const float* __restrict__ km,
                            const int* __restrict__ pids,
                            const int* __restrict__ idxs,
                            const int* __restrict__ negsz,
                            float* __restrict__ topv, int K) {
    __shared__ float sv[8192];
    __shared__ float rv[256];
    __shared__ int ri[256];
    int b = blockIdx.x, t = threadIdx.x;
    const float* row = km + (size_t)b * K;
    for (int i = t; i < K; i += 256) sv[i] = row[i];
    __syncthreads();
    if (t == 0) sv[pids[idxs[b]]] = -1e30f;  // masked pos never in top-k (ref: -2.0)
    int ns = *negsz; if (ns > 32) ns = 32;
    __syncthreads();
    for (int j = 0; j < ns; ++j) {
        float best = -1e30f; int bi = 0;
        for (int i = t; i < K; i += 256) {
            float v = sv[i];
            if (v > best) { best = v; bi = i; }
        }
        rv[t] = best; ri[t] = bi;
        __syncthreads();
        for (int s = 128; s > 0; s >>= 1) {
            if (t < s && rv[t + s] > rv[t]) { rv[t] = rv[t + s]; ri[t] = ri[t + s]; }
            __syncthreads();
        }
        if (t == 0) { topv[b * 32 + j] = rv[0]; sv[ri[0]] = -1e30f; }
        __syncthreads();
    }
}

// ---------- kernel 4: confidence mask + losses + final scalar ----------
__global__ void final_kernel(const float* __restrict__ S,
                             const float* __restrict__ pos,
                             const float* __restrict__ topv,
                             const int* __restrict__ pids,
                             const int* __restrict__ idxs,
                             const int* __restrict__ negsz,
                             float* __restrict__ out, int B) {
    __shared__ int pid_sh[256];
    __shared__ int mode_sh[16];
    __shared__ float red[256];
    int t = threadIdx.x;
    if (t < B) pid_sh[t] = pids[idxs[t]];
    __syncthreads();
    int half = B >> 1;
    int G = half / 16;   // groups of NUM_INSTANCES=16
    if (t < G) {
        int bestPid = 0x7FFFFFFF, bestCnt = -1;
        for (int i = 0; i < 16; ++i) {
            int p = pid_sh[t * 16 + i];
            int c = 0;
            for (int j = 0; j < 16; ++j) c += (pid_sh[t * 16 + j] == p) ? 1 : 0;
            if (c > bestCnt || (c == bestCnt && p < bestPid)) { bestCnt = c; bestPid = p; }
        }
        mode_sh[t] = bestPid;  // ties -> smallest id, matches bincount().argmax()
    }
    __syncthreads();
    float contrib = 0.f;
    if (t < B) {
        int hb = (t < half) ? t : t - half;
        float mask = (pid_sh[hb] == mode_sh[hb / 16]) ? 1.f : 0.f;
        int ns = *negsz; if (ns > 32) ns = 32;
        float p20 = pos[t] * 20.0f;
        float m = p20;
        for (int j = 0; j < ns; ++j) m = fmaxf(m, topv[t * 32 + j] * 20.0f);
        float se = __expf(p20 - m);
        for (int j = 0; j < ns; ++j) se += __expf(topv[t * 32 + j] * 20.0f - m);
        float ce_neg = m + logf(se) - p20;
        float ce_main = logf(S[t]) - p20;
        contrib = (0.2f * mask * ce_neg + ce_main) / (float)B;
    }
    red[t] = contrib;
    __syncthreads();
    for (int s = 128; s > 0; s >>= 1) {
        if (t < s) red[t] += red[t + s];
        __syncthreads();
    }
    if (t == 0) out[0] = red[0];
}

// ---------- launcher ----------
extern "C" void kernel_launch(void* const* d_in, const int* in_sizes, int n_in,
                              void* d_out, int out_size, void* d_ws, size_t ws_size,
                              hipStream_t stream) {
    const float* inputs   = (const float*)d_in[0];
    const float* features = (const float*)d_in[1];
    const float* cents    = (const float*)d_in[2];
    const int*   targets  = (const int*)d_in[3];
    const int*   pids     = (const int*)d_in[4];
    const int*   idxs     = (const int*)d_in[5];
    const int*   negsz    = (const int*)d_in[6];
    float* out = (float*)d_out;

    int Bb = in_sizes[3];            // 256
    int Dd = in_sizes[0] / Bb;       // 2048
    int Nn = in_sizes[1] / Dd;       // 32768
    int Kk = in_sizes[2] / Dd;       // 8192

    char* ws = (char*)d_ws;
    unsigned short* xb = (unsigned short*)ws;
    size_t o = (size_t)Bb * Dd * 2;
    float* km   = (float*)(ws + o); o += (size_t)Bb * Kk * 4;
    float* S    = (float*)(ws + o); o += (size_t)Bb * 4;
    float* pos  = (float*)(ws + o); o += (size_t)Bb * 4;
    float* topv = (float*)(ws + o); o += (size_t)Bb * 32 * 4;

    hipMemsetAsync(S, 0, (size_t)Bb * 4, stream);
    norm_kernel<<<Bb, 256, 0, stream>>>(inputs, xb, Dd);
    int nbF = Nn / 64, nbC = Kk / 64;
    gemm_kernel<<<nbF + nbC, 256, 0, stream>>>(xb, features, cents, targets,
                                               S, pos, km, Dd, Nn, Kk, nbF);
    topk_kernel<<<Bb, 256, 0, stream>>>(km, pids, idxs, negsz, topv, Kk);
    final_kernel<<<1, 256, 0, stream>>>(S, pos, topv, pids, idxs, negsz, out, Bb);
}

// Round 2
// 493.870 us; speedup vs baseline: 1.1224x; 1.1224x over previous
//
#include <hip/hip_runtime.h>
#include <stdint.h>

typedef __attribute__((ext_vector_type(8))) short short8;
typedef __attribute__((ext_vector_type(4))) float floatx4;

// ---------- helpers ----------
__device__ __forceinline__ unsigned short f2b(float f) {
    union { float f; uint32_t u; } v; v.f = f;
    uint32_t u = v.u;
    return (unsigned short)((u + 0x7FFFu + ((u >> 16) & 1u)) >> 16);  // RNE
}

// pack two fp32 -> two bf16 (round-half-up; bias negligible at threshold)
__device__ __forceinline__ uint32_t pk2(float a, float b) {
    union { float f; uint32_t u; } x, y; x.f = a; y.f = b;
    uint32_t ua = x.u + 0x8000u, ub = y.u + 0x8000u;
    return (ua >> 16) | (ub & 0xFFFF0000u);
}

__device__ __forceinline__ void async16(const void* g, void* l) {
    __builtin_amdgcn_global_load_lds(
        (const __attribute__((address_space(1))) void*)g,
        (__attribute__((address_space(3))) void*)l, 16, 0, 0);
}

// ---------- kernel 1: L2-normalize rows, emit bf16 ----------
__global__ void norm_kernel(const float* __restrict__ in,
                            unsigned short* __restrict__ xb, int D) {
    int b = blockIdx.x, t = threadIdx.x;
    const float* row = in + (size_t)b * D;
    float ss = 0.f;
    for (int i = t * 4; i < D; i += 1024) {
        float4 v = *(const float4*)(row + i);
        ss += v.x * v.x + v.y * v.y + v.z * v.z + v.w * v.w;
    }
    for (int off = 32; off > 0; off >>= 1) ss += __shfl_down(ss, off);
    __shared__ float wsum[4];
    __shared__ float rn_sh;
    if ((t & 63) == 0) wsum[t >> 6] = ss;
    __syncthreads();
    if (t == 0) rn_sh = rsqrtf(wsum[0] + wsum[1] + wsum[2] + wsum[3]);
    __syncthreads();
    float rn = rn_sh;
    unsigned short* orow = xb + (size_t)b * D;
    for (int i = t * 4; i < D; i += 1024) {
        float4 v = *(const float4*)(row + i);
        ushort4 o;
        o.x = f2b(v.x * rn); o.y = f2b(v.y * rn);
        o.z = f2b(v.z * rn); o.w = f2b(v.w * rn);
        *(ushort4*)(orow + i) = o;
    }
}

// ---------- kernel 2: fused GEMM ----------
// BM=256 (full batch, B-matrix read exactly once), BN=64, BK=64.
// LDS rows are 128 B (=32 banks); 16 B chunk c of row r stored at slot
// c ^ (r&7)  ->  every b128 read/write phase is <=2-way (free).
#define BKk 64
__global__ __launch_bounds__(256, 2)
void gemm_kernel(const unsigned short* __restrict__ xb,
                 const float* __restrict__ featB,
                 const float* __restrict__ centB,
                 const int* __restrict__ targets,
                 float* __restrict__ S, float* __restrict__ pos,
                 float* __restrict__ km,
                 int D, int K, int nbF) {
    __shared__ __align__(16) unsigned short Alds[256 * BKk];  // 32 KB
    __shared__ __align__(16) unsigned short Blds[64 * BKk];   // 8 KB

    const int t = threadIdx.x;
    const int w = t >> 6, l = t & 63;
    const bool isFeat = ((int)blockIdx.x < nbF);
    const int n0 = (isFeat ? (int)blockIdx.x : ((int)blockIdx.x - nbF)) * 64;
    const float* Bsrc = isFeat ? featB : centB;

    floatx4 acc[4][4];
#pragma unroll
    for (int ti = 0; ti < 4; ++ti)
#pragma unroll
        for (int tj = 0; tj < 4; ++tj)
            acc[ti][tj] = (floatx4){0.f, 0.f, 0.f, 0.f};

    const int kIters = D / BKk;                       // 32
    const int brow = t >> 2, bq = t & 3;              // B staging: 4 thr/row
    const float* bg0 = Bsrc + (size_t)(n0 + brow) * D + bq * 16;
    const int bc0 = ((bq * 2) ^ (brow & 7)) * 16;     // swizzled chunk slots
    const int bc1 = ((bq * 2 + 1) ^ (brow & 7)) * 16;
    const char* xbB = (const char*)xb;

    for (int kt = 0; kt < kIters; ++kt) {
        // ---- stage A: 32 KB via direct-to-LDS; swizzle folded into source addr
#pragma unroll
        for (int j = 0; j < 8; ++j) {
            int slin = j * 256 + t;                   // 16 B slot index
            int r = slin >> 3;                        // A row (0..255)
            int cg = (slin & 7) ^ (r & 7);            // global chunk for this slot
            async16(xbB + (size_t)r * (D * 2) + kt * (BKk * 2) + cg * 16,
                    (char*)Alds + slin * 16);
        }
        // ---- stage B: fp32 -> bf16, swizzled ds_write_b128 x2
        {
            const float* bg = bg0 + kt * BKk;
            float4 f0 = *(const float4*)(bg);
            float4 f1 = *(const float4*)(bg + 4);
            float4 f2 = *(const float4*)(bg + 8);
            float4 f3 = *(const float4*)(bg + 12);
            uint4 p0, p1;
            p0.x = pk2(f0.x, f0.y); p0.y = pk2(f0.z, f0.w);
            p0.z = pk2(f1.x, f1.y); p0.w = pk2(f1.z, f1.w);
            p1.x = pk2(f2.x, f2.y); p1.y = pk2(f2.z, f2.w);
            p1.z = pk2(f3.x, f3.y); p1.w = pk2(f3.z, f3.w);
            char* bb = (char*)Blds + brow * 128;
            *(uint4*)(bb + bc0) = p0;
            *(uint4*)(bb + bc1) = p1;
        }
        __syncthreads();

        // ---- compute: 2 sub-steps of K=32, 16 MFMA each
#pragma unroll
        for (int s = 0; s < 2; ++s) {
            short8 aF[4], bF[4];
#pragma unroll
            for (int ti = 0; ti < 4; ++ti) {
                int R = w * 64 + ti * 16 + (l & 15);
                int g = s * 4 + (l >> 4);
                aF[ti] = *(const short8*)((const char*)Alds +
                          R * 128 + ((g ^ (R & 7)) * 16));
            }
#pragma unroll
            for (int tj = 0; tj < 4; ++tj) {
                int Rn = tj * 16 + (l & 15);
                int g = s * 4 + (l >> 4);
                bF[tj] = *(const short8*)((const char*)Blds +
                          Rn * 128 + ((g ^ (Rn & 7)) * 16));
            }
#pragma unroll
            for (int ti = 0; ti < 4; ++ti)
#pragma unroll
                for (int tj = 0; tj < 4; ++tj)
                    acc[ti][tj] = __builtin_amdgcn_mfma_f32_16x16x32_bf16(
                        aF[ti], bF[tj], acc[ti][tj], 0, 0, 0);
        }
        __syncthreads();
    }

    // epilogue.  C/D layout: col = l&15, row = (l>>4)*4 + reg  [m89-verified]
    if (isFeat) {
#pragma unroll
        for (int ti = 0; ti < 4; ++ti) {
#pragma unroll
            for (int r = 0; r < 4; ++r) {
                int row = w * 64 + ti * 16 + ((l >> 4) << 2) + r;
                int tr = targets[row];
                int col0 = n0 + (l & 15);
                float e = 0.f;
#pragma unroll
                for (int tj = 0; tj < 4; ++tj) {
                    float c = acc[ti][tj][r];
                    e += __expf(c * 20.0f);            // |c|<=~1 -> safe
                    if (tr == col0 + tj * 16) pos[row] = c;
                }
                e += __shfl_xor(e, 1); e += __shfl_xor(e, 2);
                e += __shfl_xor(e, 4); e += __shfl_xor(e, 8);
                if ((l & 15) == 0) atomicAdd(&S[row], e);
            }
        }
    } else {
#pragma unroll
        for (int ti = 0; ti < 4; ++ti) {
#pragma unroll
            for (int r = 0; r < 4; ++r) {
                int row = w * 64 + ti * 16 + ((l >> 4) << 2) + r;
                size_t base = (size_t)row * K + n0 + (l & 15);
#pragma unroll
                for (int tj = 0; tj < 4; ++tj)
                    km[base + tj * 16] = acc[ti][tj][r];
            }
        }
    }
}

// ---------- kernel 3: per-row top-neg_size (register-resident selection) ----
// Thread t owns elements k*256+t (k=0..31) in registers.  Per extraction:
// shuffle-reduce block argmax, owner lane clears + rescans locally.
__global__ __launch_bounds__(256, 4)
void topk_kernel(const float* __restrict__ kmr,
                 const int* __restrict__ pids,
                 const int* __restrict__ idxs,
                 const int* __restrict__ negsz,
                 float* __restrict__ topv, int K) {
    int b = blockIdx.x, t = threadIdx.x;
    int w = t >> 6, l = t & 63;
    const float* row = kmr + (size_t)b * K;
    float v[32];
#pragma unroll
    for (int k = 0; k < 32; ++k) v[k] = row[k * 256 + t];
    int gi = pids[idxs[b]];          // masked position (never top-20 in ref)
    if ((gi & 255) == t) {
        int kk = gi >> 8;
#pragma unroll
        for (int k = 0; k < 32; ++k) if (k == kk) v[k] = -1e30f;
    }
    float bv = v[0]; int bk = 0;
#pragma unroll
    for (int k = 1; k < 32; ++k) if (v[k] > bv) { bv = v[k]; bk = k; }

    __shared__ float rv[4];
    __shared__ int rg[4];
    int ns = *negsz; if (ns > 32) ns = 32;
    for (int j = 0; j < ns; ++j) {
        float mv = bv; int mg = bk * 256 + t;
#pragma unroll
        for (int off = 1; off < 64; off <<= 1) {
            float ov = __shfl_xor(mv, off);
            int og = __shfl_xor(mg, off);
            if (ov > mv) { mv = ov; mg = og; }
        }
        if (l == 0) { rv[w] = mv; rg[w] = mg; }
        __syncthreads();
        float gv = rv[0]; int gg = rg[0];
#pragma unroll
        for (int ww = 1; ww < 4; ++ww)
            if (rv[ww] > gv) { gv = rv[ww]; gg = rg[ww]; }
        if (t == 0) topv[b * 32 + j] = gv;
        if ((gg & 255) == t) {
            int kk = gg >> 8;
#pragma unroll
            for (int k = 0; k < 32; ++k) if (k == kk) v[k] = -1e30f;
            bv = v[0]; bk = 0;
#pragma unroll
            for (int k = 1; k < 32; ++k) if (v[k] > bv) { bv = v[k]; bk = k; }
        }
        __syncthreads();
    }
}

// ---------- kernel 4: confidence mask + losses + final scalar ----------
__global__ void final_kernel(const float* __restrict__ S,
                             const float* __restrict__ pos,
                             const float* __restrict__ topv,
                             const int* __restrict__ pids,
                             const int* __restrict__ idxs,
                             const int* __restrict__ negsz,
                             float* __restrict__ out, int B) {
    __shared__ int pid_sh[256];
    __shared__ int mode_sh[16];
    __shared__ float red[256];
    int t = threadIdx.x;
    if (t < B) pid_sh[t] = pids[idxs[t]];
    __syncthreads();
    int half = B >> 1;
    int G = half / 16;
    if (t < G) {
        int bestPid = 0x7FFFFFFF, bestCnt = -1;
        for (int i = 0; i < 16; ++i) {
            int p = pid_sh[t * 16 + i];
            int c = 0;
            for (int j = 0; j < 16; ++j) c += (pid_sh[t * 16 + j] == p) ? 1 : 0;
            if (c > bestCnt || (c == bestCnt && p < bestPid)) { bestCnt = c; bestPid = p; }
        }
        mode_sh[t] = bestPid;  // ties -> smallest id == bincount().argmax()
    }
    __syncthreads();
    float contrib = 0.f;
    if (t < B) {
        int hb = (t < half) ? t : t - half;
        float mask = (pid_sh[hb] == mode_sh[hb / 16]) ? 1.f : 0.f;
        int ns = *negsz; if (ns > 32) ns = 32;
        float p20 = pos[t] * 20.0f;
        float m = p20;
        for (int j = 0; j < ns; ++j) m = fmaxf(m, topv[t * 32 + j] * 20.0f);
        float se = __expf(p20 - m);
        for (int j = 0; j < ns; ++j) se += __expf(topv[t * 32 + j] * 20.0f - m);
        float ce_neg = m + logf(se) - p20;
        float ce_main = logf(S[t]) - p20;
        contrib = (0.2f * mask * ce_neg + ce_main) / (float)B;
    }
    red[t] = contrib;
    __syncthreads();
    for (int s = 128; s > 0; s >>= 1) {
        if (t < s) red[t] += red[t + s];
        __syncthreads();
    }
    if (t == 0) out[0] = red[0];
}

// ---------- launcher ----------
extern "C" void kernel_launch(void* const* d_in, const int* in_sizes, int n_in,
                              void* d_out, int out_size, void* d_ws, size_t ws_size,
                              hipStream_t stream) {
    const float* inputs   = (const float*)d_in[0];
    const float* features = (const float*)d_in[1];
    const float* cents    = (const float*)d_in[2];
    const int*   targets  = (const int*)d_in[3];
    const int*   pids     = (const int*)d_in[4];
    const int*   idxs     = (const int*)d_in[5];
    const int*   negsz    = (const int*)d_in[6];
    float* out = (float*)d_out;

    int Bb = in_sizes[3];            // 256
    int Dd = in_sizes[0] / Bb;       // 2048
    int Nn = in_sizes[1] / Dd;       // 32768
    int Kk = in_sizes[2] / Dd;       // 8192

    char* ws = (char*)d_ws;
    unsigned short* xb = (unsigned short*)ws;
    size_t o = (size_t)Bb * Dd * 2;
    float* km   = (float*)(ws + o); o += (size_t)Bb * Kk * 4;
    float* S    = (float*)(ws + o); o += (size_t)Bb * 4;
    float* pos  = (float*)(ws + o); o += (size_t)Bb * 4;
    float* topv = (float*)(ws + o); o += (size_t)Bb * 32 * 4;

    hipMemsetAsync(S, 0, (size_t)Bb * 4, stream);
    norm_kernel<<<Bb, 256, 0, stream>>>(inputs, xb, Dd);
    int nbF = Nn / 64, nbC = Kk / 64;
    gemm_kernel<<<nbF + nbC, 256, 0, stream>>>(xb, features, cents, targets,
                                               S, pos, km, Dd, Kk, nbF);
    topk_kernel<<<Bb, 256, 0, stream>>>(km, pids, idxs, negsz, topv, Kk);
    final_kernel<<<1, 256, 0, stream>>>(S, pos, topv, pids, idxs, negsz, out, Bb);
}